// Round 11
// baseline (111.568 us; speedup 1.0000x reference)
//
#include <hip/hip_runtime.h>
#include <math.h>

#define BB 2
#define HH 256
#define WW 832
#define HWIMG (HH * WW)

#define TX2 52            // 16-px tiles in x (832/16)
#define TY2 16            // 16-px tiles in y (256/16)
#define ECAP 256          // per-block keeper capacity (expect ~18 in 36x36)

// ---------------------------------------------------------------------------
// Orientation at (i,j): 3x3 wrap box-blur (jnp.roll) -> jnp.gradient
// (one-sided at borders) -> atan2. Box sums of 0/1 exact in fp32; all 25
// loads independent -> one memory round trip. Bit-identical to dense pass.
// ---------------------------------------------------------------------------
__device__ inline float theta_at(const float* __restrict__ m, int i, int j) {
    int ri[5], cj[5];
#pragma unroll
    for (int t = 0; t < 5; ++t) {
        int r = i + t - 2; r = (r < 0) ? r + HH : (r >= HH ? r - HH : r);
        int c = j + t - 2; c = (c < 0) ? c + WW : (c >= WW ? c - WW : c);
        ri[t] = r * WW; cj[t] = c;
    }
    float S[5][5];
#pragma unroll
    for (int a = 0; a < 5; ++a)
#pragma unroll
        for (int c = 0; c < 5; ++c)
            S[a][c] = m[ri[a] + cj[c]];
    float ct[5], cm[5], cb[5];
#pragma unroll
    for (int c = 0; c < 5; ++c) {
        ct[c] = S[0][c] + S[1][c] + S[2][c];
        cm[c] = S[1][c] + S[2][c] + S[3][c];
        cb[c] = S[2][c] + S[3][c] + S[4][c];
    }
    float Bm = ct[1] + ct[2] + ct[3];
    float Bp = cb[1] + cb[2] + cb[3];
    float Bl = cm[0] + cm[1] + cm[2];
    float Br = cm[2] + cm[3] + cm[4];
    float Bc = cm[1] + cm[2] + cm[3];
    float gy = (i == 0) ? (Bp - Bc) : (i == HH - 1) ? (Bc - Bm) : 0.5f * (Bp - Bm);
    float gx = (j == 0) ? (Br - Bc) : (j == WW - 1) ? (Bc - Bl) : 0.5f * (Br - Bl);
    return atan2f(gy, gx);
}

// ---------------------------------------------------------------------------
// Single kernel, one block per 16x16 output tile (1664 blocks). Each block is
// fully self-contained (reads global directly; redundancy absorbed by L2):
//   1: keeper detect over its 36x36 influence region (tile +-10), ~5 px/thr
//   2: wave-per-keeper 105-offset search (lex (score,k) argmin == jnp.argmin)
//   3: 21x21 diffusion of the block-local candidate list, 1 px/thread
// No workspace, no global atomics, no cross-block communication.
// ---------------------------------------------------------------------------
__global__ void bnmorph_kernel(const float* __restrict__ src, const float* __restrict__ dst,
                               const int* __restrict__ xx, const int* __restrict__ yy, int K,
                               float* __restrict__ out) {
    __shared__ int kox[128], koy[128];
    __shared__ float kd[128];
    __shared__ float wt[441];
    __shared__ float4 ent[ECAP];   // (gj, gi, ts->dx, ->dy); x=-1e4 if inactive
    __shared__ int nkeep;

    int tid = threadIdx.x;
    if (tid == 0) nkeep = 0;
    for (int t = tid; t < K; t += 256) {
        int ox = xx[t], oy = yy[t];
        kox[t] = ox; koy[t] = oy;
        kd[t] = 20.0f * sqrtf((float)(ox * ox + oy * oy));
    }
    for (int t = tid; t < 441; t += 256) {
        int dy = t / 21 - 10;
        int dx = t % 21 - 10;
        wt[t] = expf(-sqrtf((float)(dx * dx + dy * dy)) / 5.0f);
    }
    __syncthreads();

    int ti = blockIdx.y * 16, tj = blockIdx.x * 16;
    int b = blockIdx.z;
    const float* sb = src + b * HWIMG;
    const float* db = dst + b * HWIMG;

    // ---- Phase 1: keeper detection over the 36x36 influence region ----
    for (int t = tid; t < 36 * 36; t += 256) {
        int gi = ti - 10 + t / 36;
        int gj = tj - 10 + t % 36;
        if (gi < 0 || gi >= HH || gj < 0 || gj >= WW) continue;
        if (sb[gi * WW + gj] > 0.5f) {
            // smaller-lin-index nbrs: rows -2,-1 (dj -2..2), row 0 (dj -2,-1)
            float m = 0.f;
#pragma unroll
            for (int p = 0; p < 12; ++p) {
                int di = (p < 5) ? -2 : (p < 10 ? -1 : 0);
                int dj = (p < 5) ? (p - 2) : (p < 10 ? (p - 7) : (p - 12));
                int ii = gi + di, jj = gj + dj;
                bool inb = (ii >= 0) && (jj >= 0) && (jj < WW);
                float v = sb[inb ? (ii * WW + jj) : 0];
                m = fmaxf(m, inb ? v : 0.f);
            }
            if (m <= 0.5f) {
                float ts = theta_at(sb, gi, gj);
                int pos = atomicAdd(&nkeep, 1);            // LDS atomic
                if (pos < ECAP) ent[pos] = make_float4((float)gj, (float)gi, ts, 0.f);
            }
        }
    }
    __syncthreads();

    // ---- Phase 2: wave-per-keeper search ----
    int nk = (nkeep < ECAP) ? nkeep : ECAP;
    {
        int lane = tid & 63;
        int wv = tid >> 6;                  // 0..3
        for (int w = wv; w < nk; w += 4) {
            float4 E = ent[w];
            int kj = (int)E.x, ki = (int)E.y;
            float ts = E.z;

            float best = 1e9f;
            int bk = 1 << 20;
#pragma unroll
            for (int rr = 0; rr < 2; ++rr) {
                int k = lane + rr * 64;
                if (k < K) {
                    int pi = ki + koy[k], pj = kj + kox[k];
                    if (pi >= 0 && pi < HH && pj >= 0 && pj < WW && db[pi * WW + pj] > 0.5f) {
                        float td = theta_at(db, pi, pj);   // ~2 active lanes/wave
                        float sc = kd[k] + 10.5f * (1.0f - cosf(ts - td));
                        if (sc < best || (sc == best && k < bk)) { best = sc; bk = k; }
                    }
                }
            }
#pragma unroll
            for (int off = 32; off >= 1; off >>= 1) {
                float ob = __shfl_down(best, off, 64);
                int ok = __shfl_down(bk, off, 64);
                if (ob < best || (ob == best && ok < bk)) { best = ob; bk = ok; }
            }
            if (lane == 0) {
                if (best < 5e8f) {
                    ent[w].z = (float)kox[bk];
                    ent[w].w = (float)koy[bk];
                } else {
                    ent[w].x = -1e4f;       // inactive: auto-skipped by dj test
                }
            }
        }
    }
    __syncthreads();

    // ---- Phase 3: 21x21 diffusion, 1 px/thread ----
    {
        int gj = tj + (tid & 15);
        int gi = ti + (tid >> 4);
        float nx = 0.f, ny = 0.f, de = 0.f;
        for (int c = 0; c < nk; ++c) {
            float4 E = ent[c];              // broadcast LDS read
            int dj = (int)E.x - gj;
            int di = (int)E.y - gi;
            if (dj >= -10 && dj <= 10 && di >= -10 && di <= 10) {
                float w = wt[(di + 10) * 21 + dj + 10];
                de += w; nx += w * E.z; ny += w * E.w;
            }
        }
        float inv = 0.6f / (de + 1e-6f);
        int obase = b * 2 * HWIMG;
        out[obase + gi * WW + gj] = (float)gj + nx * inv;
        out[obase + HWIMG + gi * WW + gj] = (float)gi + ny * inv;
    }
}

// ---------------------------------------------------------------------------
extern "C" void kernel_launch(void* const* d_in, const int* in_sizes, int n_in,
                              void* d_out, int out_size, void* d_ws, size_t ws_size,
                              hipStream_t stream) {
    const float* src = (const float*)d_in[0];
    const float* dst = (const float*)d_in[1];
    const int* xx = (const int*)d_in[2];
    const int* yy = (const int*)d_in[3];
    int K = in_sizes[2];  // 105

    bnmorph_kernel<<<dim3(TX2, TY2, BB), dim3(256), 0, stream>>>(
        src, dst, xx, yy, K, (float*)d_out);
}

// Round 12
// 91.881 us; speedup vs baseline: 1.2143x; 1.2143x over previous
//
#include <hip/hip_runtime.h>
#include <math.h>

#define BB 2
#define HH 256
#define WW 832
#define HWIMG (HH * WW)

#define TX2 52            // 16-px tiles in x (832/16)
#define TY2 16            // 16-px tiles in y (256/16)
#define SEG 64            // per-tile keeper-result capacity (expect ~5)
#define ECAP 192          // diffuse candidate capacity (expect ~25)

// ---------------------------------------------------------------------------
// Orientation at (i,j): 3x3 wrap box-blur (jnp.roll) -> jnp.gradient
// (one-sided at borders) -> atan2. Box sums of 0/1 exact in fp32; all 25
// loads independent -> one memory round trip. Bit-identical to dense pass.
// ---------------------------------------------------------------------------
__device__ inline float theta_at(const float* __restrict__ m, int i, int j) {
    int ri[5], cj[5];
#pragma unroll
    for (int t = 0; t < 5; ++t) {
        int r = i + t - 2; r = (r < 0) ? r + HH : (r >= HH ? r - HH : r);
        int c = j + t - 2; c = (c < 0) ? c + WW : (c >= WW ? c - WW : c);
        ri[t] = r * WW; cj[t] = c;
    }
    float S[5][5];
#pragma unroll
    for (int a = 0; a < 5; ++a)
#pragma unroll
        for (int c = 0; c < 5; ++c)
            S[a][c] = m[ri[a] + cj[c]];
    float ct[5], cm[5], cb[5];
#pragma unroll
    for (int c = 0; c < 5; ++c) {
        ct[c] = S[0][c] + S[1][c] + S[2][c];
        cm[c] = S[1][c] + S[2][c] + S[3][c];
        cb[c] = S[2][c] + S[3][c] + S[4][c];
    }
    float Bm = ct[1] + ct[2] + ct[3];
    float Bp = cb[1] + cb[2] + cb[3];
    float Bl = cm[0] + cm[1] + cm[2];
    float Br = cm[2] + cm[3] + cm[4];
    float Bc = cm[1] + cm[2] + cm[3];
    float gy = (i == 0) ? (Bp - Bc) : (i == HH - 1) ? (Bc - Bm) : 0.5f * (Bp - Bm);
    float gx = (j == 0) ? (Br - Bc) : (j == WW - 1) ? (Bc - Bl) : 0.5f * (Br - Bl);
    return atan2f(gy, gx);
}

// ---------------------------------------------------------------------------
// Kernel A: one block per 16x16 tile. Keeper detect (own tile only) ->
// wave-per-keeper 105-offset search (global L1/L2 reads) -> owner-writes
// seg[tile]/cnt[tile]. No global atomics; no init required.
// packed: j(10b) | i<<10(8b) | b<<18(1b) | (dx+7)<<19(4b) | (dy+3)<<23(3b);
// -1 = keeper with no hit (inactive).
// ---------------------------------------------------------------------------
__global__ void prep_search_kernel(const float* __restrict__ src, const float* __restrict__ dst,
                                   const int* __restrict__ xx, const int* __restrict__ yy, int K,
                                   int* __restrict__ cnt, int* __restrict__ seg) {
    __shared__ int kox[128], koy[128];
    __shared__ float kd[128];
    __shared__ int recs[SEG];
    __shared__ float tss[SEG];
    __shared__ int outv[SEG];
    __shared__ int nkeep;

    int tid = threadIdx.x;
    if (tid == 0) nkeep = 0;
    for (int t = tid; t < K; t += 256) {
        int ox = xx[t], oy = yy[t];
        kox[t] = ox; koy[t] = oy;
        kd[t] = 20.0f * sqrtf((float)(ox * ox + oy * oy));
    }
    __syncthreads();

    int txi = blockIdx.x, tyi = blockIdx.y, b = blockIdx.z;
    int gi = tyi * 16 + (tid >> 4);
    int gj = txi * 16 + (tid & 15);
    const float* sb = src + b * HWIMG;
    const float* db = dst + b * HWIMG;

    // ---- Phase 1: keeper detection on own pixel ----
    if (sb[gi * WW + gj] > 0.5f) {
        // smaller-lin-index nbrs: rows -2,-1 (dj -2..2), row 0 (dj -2,-1)
        float m = 0.f;
#pragma unroll
        for (int p = 0; p < 12; ++p) {
            int di = (p < 5) ? -2 : (p < 10 ? -1 : 0);
            int dj = (p < 5) ? (p - 2) : (p < 10 ? (p - 7) : (p - 12));
            int ii = gi + di, jj = gj + dj;
            bool inb = (ii >= 0) && (jj >= 0) && (jj < WW);
            float v = sb[inb ? (ii * WW + jj) : 0];
            m = fmaxf(m, inb ? v : 0.f);
        }
        if (m <= 0.5f) {
            float ts = theta_at(sb, gi, gj);
            int pos = atomicAdd(&nkeep, 1);        // LDS atomic
            if (pos < SEG) { recs[pos] = gj | (gi << 10); tss[pos] = ts; }
        }
    }
    __syncthreads();

    // ---- Phase 2: wave-per-keeper search (lex (score,k) argmin) ----
    int nk = (nkeep < SEG) ? nkeep : SEG;
    int lane = tid & 63;
    int wv = tid >> 6;
    for (int w = wv; w < nk; w += 4) {
        int rec = recs[w];
        int kj = rec & 1023;
        int ki = rec >> 10;
        float ts = tss[w];

        float best = 1e9f;
        int bk = 1 << 20;
#pragma unroll
        for (int rr = 0; rr < 2; ++rr) {
            int k = lane + rr * 64;
            if (k < K) {
                int pi = ki + koy[k], pj = kj + kox[k];
                if (pi >= 0 && pi < HH && pj >= 0 && pj < WW && db[pi * WW + pj] > 0.5f) {
                    float td = theta_at(db, pi, pj);   // ~2 active lanes/wave
                    float sc = kd[k] + 10.5f * (1.0f - cosf(ts - td));
                    if (sc < best || (sc == best && k < bk)) { best = sc; bk = k; }
                }
            }
        }
#pragma unroll
        for (int off = 32; off >= 1; off >>= 1) {
            float ob = __shfl_down(best, off, 64);
            int ok = __shfl_down(bk, off, 64);
            if (ob < best || (ob == best && ok < bk)) { best = ob; bk = ok; }
        }
        if (lane == 0)
            outv[w] = (best < 5e8f)
                ? (rec | (b << 18) | ((kox[bk] + 7) << 19) | ((koy[bk] + 3) << 23))
                : -1;
    }
    __syncthreads();

    // ---- Owner-writes segment (no atomics, no init needed) ----
    int tile = (b * TY2 + tyi) * TX2 + txi;
    if (tid < nk) seg[tile * SEG + tid] = outv[tid];
    if (tid == 0) cnt[tile] = nk;
}

// ---------------------------------------------------------------------------
// Kernel B: one block per 16x16 tile. Gather 3x3 neighbor segments (+-10<16)
// into LDS, then 21x21 weighted diffusion, 1 px/thread.
// ---------------------------------------------------------------------------
__global__ void diffuse_kernel(const int* __restrict__ cnt, const int* __restrict__ seg,
                               float* __restrict__ out) {
    __shared__ float wt[441];
    __shared__ float4 ent[ECAP];
    __shared__ int ncnt[9];
    __shared__ int ne;

    int tid = threadIdx.x;
    if (tid == 0) ne = 0;
    for (int t = tid; t < 441; t += 256) {
        int dy = t / 21 - 10;
        int dx = t % 21 - 10;
        wt[t] = expf(-sqrtf((float)(dx * dx + dy * dy)) / 5.0f);
    }
    int txi = blockIdx.x, tyi = blockIdx.y, b = blockIdx.z;
    if (tid < 9) {
        int nty = tyi + tid / 3 - 1;
        int ntx = txi + tid % 3 - 1;
        ncnt[tid] = (nty >= 0 && nty < TY2 && ntx >= 0 && ntx < TX2)
                        ? cnt[(b * TY2 + nty) * TX2 + ntx] : 0;
    }
    __syncthreads();

    for (int t = tid; t < 9 * SEG; t += 256) {
        int q = t / SEG, slot = t % SEG;
        if (slot < ncnt[q]) {
            int nty = tyi + q / 3 - 1;
            int ntx = txi + q % 3 - 1;
            int v = seg[((b * TY2 + nty) * TX2 + ntx) * SEG + slot];
            if (v != -1) {
                int pos = atomicAdd(&ne, 1);       // LDS atomic
                if (pos < ECAP)
                    ent[pos] = make_float4((float)(v & 1023), (float)((v >> 10) & 255),
                                           (float)(((v >> 19) & 15) - 7),
                                           (float)(((v >> 23) & 7) - 3));
            }
        }
    }
    __syncthreads();

    int nn = (ne < ECAP) ? ne : ECAP;
    int gj = txi * 16 + (tid & 15);
    int gi = tyi * 16 + (tid >> 4);
    float nx = 0.f, ny = 0.f, de = 0.f;
    for (int c = 0; c < nn; ++c) {
        float4 E = ent[c];                          // broadcast LDS read
        int dj = (int)E.x - gj;
        int di = (int)E.y - gi;
        if (dj >= -10 && dj <= 10 && di >= -10 && di <= 10) {
            float w = wt[(di + 10) * 21 + dj + 10];
            de += w; nx += w * E.z; ny += w * E.w;
        }
    }
    float inv = 0.6f / (de + 1e-6f);
    int obase = b * 2 * HWIMG;
    out[obase + gi * WW + gj] = (float)gj + nx * inv;
    out[obase + HWIMG + gi * WW + gj] = (float)gi + ny * inv;
}

// ---------------------------------------------------------------------------
extern "C" void kernel_launch(void* const* d_in, const int* in_sizes, int n_in,
                              void* d_out, int out_size, void* d_ws, size_t ws_size,
                              hipStream_t stream) {
    const float* src = (const float*)d_in[0];
    const float* dst = (const float*)d_in[1];
    const int* xx = (const int*)d_in[2];
    const int* yy = (const int*)d_in[3];
    int K = in_sizes[2];  // 105

    int* cnt = (int*)d_ws;                          // [BB*TY2*TX2]
    int* seg = cnt + BB * TY2 * TX2;                // [BB*TY2*TX2*SEG]
    float* out = (float*)d_out;

    dim3 grid(TX2, TY2, BB);
    prep_search_kernel<<<grid, dim3(256), 0, stream>>>(src, dst, xx, yy, K, cnt, seg);
    diffuse_kernel<<<grid, dim3(256), 0, stream>>>(cnt, seg, out);
}